// Round 3
// baseline (453.948 us; speedup 1.0000x reference)
//
#include <hip/hip_runtime.h>

#define D 128
#define TILE 256

// ---------------------------------------------------------------- degree init
__global__ __launch_bounds__(256) void k_deg_init(int* __restrict__ deg, int n) {
    int i = blockIdx.x * 256 + threadIdx.x;
    if (i < n) deg[i] = 1;  // self-loop
}

// ---------------------------------------------------------------- degree count
__global__ __launch_bounds__(256) void k_count(const int* __restrict__ col, int* __restrict__ deg, int E) {
    int e = blockIdx.x * 256 + threadIdx.x;
    if (e < E) atomicAdd(&deg[col[e]], 1);
}

// ---------------------------------------------------------------- scan phase 1: per-tile sum of (deg-1)
__global__ __launch_bounds__(TILE) void k_tilesum(const int* __restrict__ deg, int* __restrict__ tileSum, int n) {
    __shared__ int s[TILE];
    int t = threadIdx.x;
    int i = blockIdx.x * TILE + t;
    s[t] = (i < n) ? deg[i] - 1 : 0;
    __syncthreads();
    for (int off = TILE / 2; off > 0; off >>= 1) {
        if (t < off) s[t] += s[t + off];
        __syncthreads();
    }
    if (t == 0) tileSum[blockIdx.x] = s[0];
}

// ---------------------------------------------------------------- scan phase 2: scan tile sums (1 block)
__global__ __launch_bounds__(TILE) void k_tilescan(const int* __restrict__ tileSum, int* __restrict__ tileBase,
                                                   int* __restrict__ total_out, int nTiles) {
    __shared__ int s[TILE];
    int t = threadIdx.x;
    int v = (t < nTiles) ? tileSum[t] : 0;
    s[t] = v;
    __syncthreads();
    for (int off = 1; off < TILE; off <<= 1) {
        int tmp = (t >= off) ? s[t - off] : 0;
        __syncthreads();
        s[t] += tmp;
        __syncthreads();
    }
    if (t < nTiles) tileBase[t] = s[t] - v;       // exclusive base per tile
    if (t == TILE - 1) total_out[0] = s[TILE - 1]; // offsets[n] = E
}

// ---------------------------------------------------------------- scan phase 3: in-tile scan -> offsets/cursor/dinv
__global__ __launch_bounds__(TILE) void k_offsets(const int* __restrict__ deg, const int* __restrict__ tileBase,
                                                  int* __restrict__ offsets, int* __restrict__ cursor,
                                                  float* __restrict__ dinv, int n) {
    __shared__ int s[TILE];
    int t = threadIdx.x;
    int i = blockIdx.x * TILE + t;
    int dg = (i < n) ? deg[i] : 1;
    int v = dg - 1;
    s[t] = v;
    __syncthreads();
    for (int off = 1; off < TILE; off <<= 1) {
        int tmp = (t >= off) ? s[t - off] : 0;
        __syncthreads();
        s[t] += tmp;
        __syncthreads();
    }
    if (i < n) {
        int excl = s[t] - v + tileBase[blockIdx.x];
        offsets[i] = excl;
        cursor[i] = excl;
        dinv[i] = rsqrtf((float)dg);
    }
}

// ---------------------------------------------------------------- CSR fill (counting sort by dst)
__global__ __launch_bounds__(256) void k_fill(const int* __restrict__ row, const int* __restrict__ col,
                                              int* __restrict__ cursor, int* __restrict__ csr, int E) {
    int e = blockIdx.x * 256 + threadIdx.x;
    if (e < E) {
        int d = col[e];
        int p = atomicAdd(&cursor[d], 1);
        csr[p] = row[e];
    }
}

// ---------------------------------------------------------------- out[r,:] = dinv[r] * (in[r,:] @ W)
// 64 rows/block, 256 threads, thread = 8 rows x 4 cols microtile.
// LDS: X tile (32 KB) + double-buffered 16-row W k-slice (2x8 KB) = 48 KB -> 3 blocks/CU.
__global__ __launch_bounds__(256) void k_gemm(const float* __restrict__ in, const float* __restrict__ W,
                                              const float* __restrict__ dinv, float* __restrict__ out, int n) {
    __shared__ float Xs[64 * D];        // 32 KB
    __shared__ float Ws[2][16 * D];     // 2 x 8 KB
    int t = threadIdx.x;
    int row0 = blockIdx.x * 64;

    // stage X tile (64 rows x 128 cols)
    const float4* X4 = (const float4*)in;
    float4* Xs4 = (float4*)Xs;
#pragma unroll
    for (int i = 0; i < 8; ++i) {
        int idx = t + i * 256;                  // 0..2047 (64 rows x 32 float4)
        int r = row0 + (idx >> 5);
        Xs4[idx] = (r < n) ? X4[(size_t)r * 32 + (idx & 31)] : make_float4(0.f, 0.f, 0.f, 0.f);
    }
    // stage W slice 0 (k rows 0..15)
    const float4* W4 = (const float4*)W;
    {
        float4* Wb = (float4*)Ws[0];
        Wb[t] = W4[t];
        Wb[t + 256] = W4[t + 256];
    }
    __syncthreads();

    int ty = t >> 5, tx = t & 31;
    int rbase = ty * 8;
    int c0 = tx * 4;
    float4 acc[8];
#pragma unroll
    for (int i = 0; i < 8; ++i) acc[i] = make_float4(0.f, 0.f, 0.f, 0.f);

    for (int s = 0; s < 8; ++s) {
        float4 wp0, wp1;
        if (s < 7) {                            // prefetch next W slice into regs
            wp0 = W4[(s + 1) * 512 + t];
            wp1 = W4[(s + 1) * 512 + t + 256];
        }
        const float* Wcur = Ws[s & 1];
#pragma unroll
        for (int kk = 0; kk < 16; kk += 4) {
            float4 w0 = *(const float4*)&Wcur[(kk + 0) * D + c0];
            float4 w1 = *(const float4*)&Wcur[(kk + 1) * D + c0];
            float4 w2 = *(const float4*)&Wcur[(kk + 2) * D + c0];
            float4 w3 = *(const float4*)&Wcur[(kk + 3) * D + c0];
            int kbase = s * 16 + kk;
#pragma unroll
            for (int i = 0; i < 8; ++i) {
                float4 xv = *(const float4*)&Xs[(rbase + i) * D + kbase];
                acc[i].x += xv.x * w0.x + xv.y * w1.x + xv.z * w2.x + xv.w * w3.x;
                acc[i].y += xv.x * w0.y + xv.y * w1.y + xv.z * w2.y + xv.w * w3.y;
                acc[i].z += xv.x * w0.z + xv.y * w1.z + xv.z * w2.z + xv.w * w3.z;
                acc[i].w += xv.x * w0.w + xv.y * w1.w + xv.z * w2.w + xv.w * w3.w;
            }
        }
        if (s < 7) {                            // commit prefetched slice
            float4* Wn = (float4*)Ws[(s + 1) & 1];
            Wn[t] = wp0;
            Wn[t + 256] = wp1;
        }
        __syncthreads();
    }

#pragma unroll
    for (int i = 0; i < 8; ++i) {
        int r = row0 + rbase + i;
        if (r < n) {
            float sc = dinv[r];
            float4 v = acc[i];
            v.x *= sc; v.y *= sc; v.z *= sc; v.w *= sc;
            *(float4*)&out[(size_t)r * D + c0] = v;
        }
    }
}

// ---------------------------------------------------------------- aggregation: one wave per node
// out[i,:] = relu(dinv[i]*(hp[i,:] + sum_{j in CSR[i]} hp[j,:]) + bias)
__global__ __launch_bounds__(256) void k_agg(const float* __restrict__ hp, const int* __restrict__ offs,
                                             const int* __restrict__ src, const float* __restrict__ dinv,
                                             const float* __restrict__ bias, float* __restrict__ out, int n) {
    int wid = (blockIdx.x * 256 + threadIdx.x) >> 6;
    int lane = threadIdx.x & 63;
    if (wid >= n) return;
    const float2* hp2 = (const float2*)hp;
    float2 acc = hp2[(size_t)wid * 64 + lane];   // self-loop contribution
    int beg = offs[wid], end = offs[wid + 1];
    int e = beg;
    for (; e + 4 <= end; e += 4) {
        int s0 = src[e], s1 = src[e + 1], s2 = src[e + 2], s3 = src[e + 3];
        float2 v0 = hp2[(size_t)s0 * 64 + lane];
        float2 v1 = hp2[(size_t)s1 * 64 + lane];
        float2 v2 = hp2[(size_t)s2 * 64 + lane];
        float2 v3 = hp2[(size_t)s3 * 64 + lane];
        acc.x += v0.x + v1.x + v2.x + v3.x;
        acc.y += v0.y + v1.y + v2.y + v3.y;
    }
    for (; e < end; ++e) {
        int s = src[e];
        float2 v = hp2[(size_t)s * 64 + lane];
        acc.x += v.x; acc.y += v.y;
    }
    float di = dinv[wid];
    float2 b = ((const float2*)bias)[lane];
    float2 o;
    o.x = fmaxf(fmaf(di, acc.x, b.x), 0.f);
    o.y = fmaxf(fmaf(di, acc.y, b.y), 0.f);
    ((float2*)out)[(size_t)wid * 64 + lane] = o;
}

// ---------------------------------------------------------------- pool init + segment max
__global__ __launch_bounds__(128) void k_pool_init(int* __restrict__ pool) {
    pool[blockIdx.x * 128 + threadIdx.x] = 0;
}

__global__ __launch_bounds__(128) void k_pool(const float* __restrict__ h, const int* __restrict__ batch,
                                              int* __restrict__ pool, int n) {
    int c = threadIdx.x;
    int nb = gridDim.x;
    int chunk = (n + nb - 1) / nb;
    int beg = blockIdx.x * chunk;
    int end = min(beg + chunk, n);
    if (beg >= end) return;
    int g = batch[beg];
    float m = h[(size_t)beg * D + c];
    for (int i = beg + 1; i < end; ++i) {
        int gi = batch[i];
        float v = h[(size_t)i * D + c];
        if (gi != g) {
            atomicMax(&pool[g * D + c], __float_as_int(m));  // relu output >= 0 -> int cmp valid
            g = gi; m = v;
        } else {
            m = fmaxf(m, v);
        }
    }
    atomicMax(&pool[g * D + c], __float_as_int(m));
}

// ---------------------------------------------------------------- final MLP + log_softmax, 1 block/graph
__global__ __launch_bounds__(128) void k_mlp(const float* __restrict__ pool, const float* __restrict__ W0,
                                             const float* __restrict__ b0, const float* __restrict__ W1,
                                             const float* __restrict__ b1, float* __restrict__ out) {
    __shared__ float rowv[128];
    __shared__ float h2[128];
    __shared__ float h3[10];
    int g = blockIdx.x, t = threadIdx.x;
    rowv[t] = pool[g * 128 + t];
    __syncthreads();
    float acc = b0[t];
    for (int k = 0; k < 128; ++k) acc = fmaf(rowv[k], W0[k * 128 + t], acc);
    h2[t] = fmaxf(acc, 0.f);
    __syncthreads();
    if (t < 10) {
        float a = b1[t];
        for (int k = 0; k < 128; ++k) a = fmaf(h2[k], W1[k * 10 + t], a);
        h3[t] = fmaxf(a, 0.f);
    }
    __syncthreads();
    if (t == 0) {
        float mx = h3[0];
        for (int j = 1; j < 10; ++j) mx = fmaxf(mx, h3[j]);
        float s = 0.f;
        for (int j = 0; j < 10; ++j) s += expf(h3[j] - mx);
        float lse = logf(s) + mx;
        for (int j = 0; j < 10; ++j) out[g * 10 + j] = h3[j] - lse;
    }
}

// ----------------------------------------------------------------
extern "C" void kernel_launch(void* const* d_in, const int* in_sizes, int n_in,
                              void* d_out, int out_size, void* d_ws, size_t ws_size,
                              hipStream_t stream) {
    const float* x   = (const float*)d_in[0];
    const int* eidx  = (const int*)d_in[1];
    const int* batch = (const int*)d_in[2];
    const float* w0  = (const float*)d_in[3];
    const float* b0  = (const float*)d_in[4];
    const float* w1  = (const float*)d_in[5];
    const float* b1  = (const float*)d_in[6];
    const float* lw0 = (const float*)d_in[7];
    const float* lb0 = (const float*)d_in[8];
    const float* lw1 = (const float*)d_in[9];
    const float* lb1 = (const float*)d_in[10];
    float* out = (float*)d_out;

    int n = in_sizes[2];
    int E = in_sizes[1] / 2;
    const int* row = eidx;        // sources
    const int* col = eidx + E;    // destinations
    int nTiles = (n + TILE - 1) / TILE;   // 196 for n=50000 (must be <= TILE)

    char* ws = (char*)d_ws;
    size_t o = 0;
    auto take = [&](size_t bytes) { void* p = ws + o; o += (bytes + 255) & ~(size_t)255; return p; };
    int*   deg      = (int*)  take((size_t)n * 4);
    int*   offsets  = (int*)  take((size_t)(n + 1) * 4);
    int*   cursor   = (int*)  take((size_t)n * 4);
    int*   csr      = (int*)  take((size_t)E * 4);
    float* dinv     = (float*)take((size_t)n * 4);
    int*   tileSum  = (int*)  take((size_t)nTiles * 4);
    int*   tileBase = (int*)  take((size_t)nTiles * 4);
    float* bufA     = (float*)take((size_t)n * D * 4);
    float* bufB     = (float*)take((size_t)n * D * 4);
    float* pool     = (float*)take(64 * D * 4);

    k_deg_init<<<(n + 255) / 256, 256, 0, stream>>>(deg, n);
    k_count<<<(E + 255) / 256, 256, 0, stream>>>(col, deg, E);
    k_tilesum<<<nTiles, TILE, 0, stream>>>(deg, tileSum, n);
    k_tilescan<<<1, TILE, 0, stream>>>(tileSum, tileBase, &offsets[n], nTiles);
    k_offsets<<<nTiles, TILE, 0, stream>>>(deg, tileBase, offsets, cursor, dinv, n);
    k_fill<<<(E + 255) / 256, 256, 0, stream>>>(row, col, cursor, csr, E);

    // conv0: h' = dinv * (x @ W0); agg -> relu
    k_gemm<<<(n + 63) / 64, 256, 0, stream>>>(x, w0, dinv, bufA, n);
    k_agg<<<(n + 3) / 4, 256, 0, stream>>>(bufA, offsets, csr, dinv, b0, bufB, n);
    // conv1
    k_gemm<<<(n + 63) / 64, 256, 0, stream>>>(bufB, w1, dinv, bufA, n);
    k_agg<<<(n + 3) / 4, 256, 0, stream>>>(bufA, offsets, csr, dinv, b1, bufB, n);

    k_pool_init<<<64, 128, 0, stream>>>((int*)pool);
    k_pool<<<512, 128, 0, stream>>>(bufB, batch, (int*)pool, n);
    k_mlp<<<64, 128, 0, stream>>>(pool, lw0, lb0, lw1, lb1, out);
}

// Round 4
// 308.544 us; speedup vs baseline: 1.4713x; 1.4713x over previous
//
#include <hip/hip_runtime.h>

#define D 128
#define TILE 256

typedef __attribute__((ext_vector_type(8))) short short8;
typedef __attribute__((ext_vector_type(4))) float f32x4;

__device__ inline unsigned short f2bf(float f) {
    unsigned u = __float_as_uint(f);
    return (unsigned short)((u + 0x7FFFu + ((u >> 16) & 1u)) >> 16);
}
__device__ inline float bflo(unsigned u) { return __uint_as_float(u << 16); }
__device__ inline float bfhi(unsigned u) { return __uint_as_float(u & 0xFFFF0000u); }

// ---------------------------------------------------------------- degree init
__global__ __launch_bounds__(256) void k_deg_init(int* __restrict__ deg, int n) {
    int i = blockIdx.x * 256 + threadIdx.x;
    if (i < n) deg[i] = 1;  // self-loop
}

// ---------------------------------------------------------------- degree count
__global__ __launch_bounds__(256) void k_count(const int* __restrict__ col, int* __restrict__ deg, int E) {
    int e = blockIdx.x * 256 + threadIdx.x;
    if (e < E) atomicAdd(&deg[col[e]], 1);
}

// ---------------------------------------------------------------- scan phase 1
__global__ __launch_bounds__(TILE) void k_tilesum(const int* __restrict__ deg, int* __restrict__ tileSum, int n) {
    __shared__ int s[TILE];
    int t = threadIdx.x;
    int i = blockIdx.x * TILE + t;
    s[t] = (i < n) ? deg[i] - 1 : 0;
    __syncthreads();
    for (int off = TILE / 2; off > 0; off >>= 1) {
        if (t < off) s[t] += s[t + off];
        __syncthreads();
    }
    if (t == 0) tileSum[blockIdx.x] = s[0];
}

// ---------------------------------------------------------------- scan phase 2 (1 block)
__global__ __launch_bounds__(TILE) void k_tilescan(const int* __restrict__ tileSum, int* __restrict__ tileBase,
                                                   int* __restrict__ total_out, int nTiles) {
    __shared__ int s[TILE];
    int t = threadIdx.x;
    int v = (t < nTiles) ? tileSum[t] : 0;
    s[t] = v;
    __syncthreads();
    for (int off = 1; off < TILE; off <<= 1) {
        int tmp = (t >= off) ? s[t - off] : 0;
        __syncthreads();
        s[t] += tmp;
        __syncthreads();
    }
    if (t < nTiles) tileBase[t] = s[t] - v;
    if (t == TILE - 1) total_out[0] = s[TILE - 1];
}

// ---------------------------------------------------------------- scan phase 3
__global__ __launch_bounds__(TILE) void k_offsets(const int* __restrict__ deg, const int* __restrict__ tileBase,
                                                  int* __restrict__ offsets, int* __restrict__ cursor,
                                                  float* __restrict__ dinv, int n) {
    __shared__ int s[TILE];
    int t = threadIdx.x;
    int i = blockIdx.x * TILE + t;
    int dg = (i < n) ? deg[i] : 1;
    int v = dg - 1;
    s[t] = v;
    __syncthreads();
    for (int off = 1; off < TILE; off <<= 1) {
        int tmp = (t >= off) ? s[t - off] : 0;
        __syncthreads();
        s[t] += tmp;
        __syncthreads();
    }
    if (i < n) {
        int excl = s[t] - v + tileBase[blockIdx.x];
        offsets[i] = excl;
        cursor[i] = excl;
        dinv[i] = rsqrtf((float)dg);
    }
}

// ---------------------------------------------------------------- CSR fill
__global__ __launch_bounds__(256) void k_fill(const int* __restrict__ row, const int* __restrict__ col,
                                              int* __restrict__ cursor, int* __restrict__ csr, int E) {
    int e = blockIdx.x * 256 + threadIdx.x;
    if (e < E) {
        int d = col[e];
        int p = atomicAdd(&cursor[d], 1);
        csr[p] = row[e];
    }
}

// ---------------------------------------------------------------- pack W0 (natural k), W1 (P1-permuted k), biases (P1 positions)
// B-fragment: entry (T,U,lane) holds B[k=T*32+(lane>>4)*8+j][n=U*16+(lane&15)], j=0..7 packed as 4 dwords.
// P1 position->col: c(p) = (p&7)*16 + (p>>3).
__global__ __launch_bounds__(256) void k_packW(const float* __restrict__ w0, const float* __restrict__ w1,
                                               const float* __restrict__ b0, const float* __restrict__ b1,
                                               uint4* __restrict__ Wp0, uint4* __restrict__ Wp1,
                                               float* __restrict__ b0p, float* __restrict__ b1p) {
    int t = threadIdx.x;
    for (int e = t; e < 2048; e += 256) {
        int l = e & 63, U = (e >> 6) & 7, T = e >> 9;
        int nn = U * 16 + (l & 15);
        int kq = T * 32 + ((l >> 4) << 3);
        unsigned r[4], s[4];
#pragma unroll
        for (int jj = 0; jj < 4; ++jj) {
            int k0 = kq + 2 * jj, k1 = k0 + 1;
            unsigned a0 = f2bf(w0[k0 * 128 + nn]), a1 = f2bf(w0[k1 * 128 + nn]);
            r[jj] = a0 | (a1 << 16);
            int c0 = ((k0 & 7) << 4) | (k0 >> 3), c1 = ((k1 & 7) << 4) | (k1 >> 3);
            unsigned q0 = f2bf(w1[c0 * 128 + nn]), q1 = f2bf(w1[c1 * 128 + nn]);
            s[jj] = q0 | (q1 << 16);
        }
        Wp0[e] = make_uint4(r[0], r[1], r[2], r[3]);
        Wp1[e] = make_uint4(s[0], s[1], s[2], s[3]);
    }
    if (t < 128) {
        int c = ((t & 7) << 4) | (t >> 3);
        b0p[t] = b0[c];
        b1p[t] = b1[c];
    }
}

// ---------------------------------------------------------------- MFMA GEMM, fp32 row-major input (conv0)
// out rows stored bf16 in P1 position order; value = dinv[r] * (x @ W)[r].
__global__ __launch_bounds__(256) void k_gemm0(const float* __restrict__ x, const uint4* __restrict__ Wp,
                                               const float* __restrict__ dinv, unsigned* __restrict__ outb, int n) {
    int wave = threadIdx.x >> 6, l = threadIdx.x & 63;
    int mt = blockIdx.x * 4 + wave;
    int r0 = mt * 16;
    if (r0 >= n) return;                    // n % 16 == 0
    int rowA = r0 + (l & 15);
    int kq = (l >> 4) * 8;
    f32x4 acc[8];
#pragma unroll
    for (int U = 0; U < 8; ++U) acc[U] = (f32x4){0.f, 0.f, 0.f, 0.f};
    const float* xr = x + (size_t)rowA * 128 + kq;
#pragma unroll
    for (int T = 0; T < 4; ++T) {
        float4 a0 = *(const float4*)(xr + T * 32);
        float4 a1 = *(const float4*)(xr + T * 32 + 4);
        short8 af;
        af[0] = (short)f2bf(a0.x); af[1] = (short)f2bf(a0.y);
        af[2] = (short)f2bf(a0.z); af[3] = (short)f2bf(a0.w);
        af[4] = (short)f2bf(a1.x); af[5] = (short)f2bf(a1.y);
        af[6] = (short)f2bf(a1.z); af[7] = (short)f2bf(a1.w);
#pragma unroll
        for (int U = 0; U < 8; ++U) {
            short8 bf = *(const short8*)&Wp[(T * 8 + U) * 64 + l];
            acc[U] = __builtin_amdgcn_mfma_f32_16x16x32_bf16(af, bf, acc[U], 0, 0, 0);
        }
    }
    int rq = l >> 4, cl = l & 15;
#pragma unroll
    for (int q = 0; q < 4; ++q) {
        int rr = r0 + rq * 4 + q;
        float d = dinv[rr];
        uint4 w;
        w.x = (unsigned)f2bf(acc[0][q] * d) | ((unsigned)f2bf(acc[1][q] * d) << 16);
        w.y = (unsigned)f2bf(acc[2][q] * d) | ((unsigned)f2bf(acc[3][q] * d) << 16);
        w.z = (unsigned)f2bf(acc[4][q] * d) | ((unsigned)f2bf(acc[5][q] * d) << 16);
        w.w = (unsigned)f2bf(acc[6][q] * d) | ((unsigned)f2bf(acc[7][q] * d) << 16);
        *(uint4*)(outb + (size_t)rr * 64 + cl * 4) = w;
    }
}

// ---------------------------------------------------------------- MFMA GEMM, bf16 P1-ordered input (conv1)
__global__ __launch_bounds__(256) void k_gemm1(const unsigned* __restrict__ inb, const uint4* __restrict__ Wp,
                                               const float* __restrict__ dinv, unsigned* __restrict__ outb, int n) {
    int wave = threadIdx.x >> 6, l = threadIdx.x & 63;
    int mt = blockIdx.x * 4 + wave;
    int r0 = mt * 16;
    if (r0 >= n) return;
    int rowA = r0 + (l & 15);
    int kq4 = (l >> 4) * 4;                 // dword offset of 8-bf16 group
    f32x4 acc[8];
#pragma unroll
    for (int U = 0; U < 8; ++U) acc[U] = (f32x4){0.f, 0.f, 0.f, 0.f};
    const unsigned* ir = inb + (size_t)rowA * 64 + kq4;
#pragma unroll
    for (int T = 0; T < 4; ++T) {
        short8 af = *(const short8*)(ir + T * 16);
#pragma unroll
        for (int U = 0; U < 8; ++U) {
            short8 bf = *(const short8*)&Wp[(T * 8 + U) * 64 + l];
            acc[U] = __builtin_amdgcn_mfma_f32_16x16x32_bf16(af, bf, acc[U], 0, 0, 0);
        }
    }
    int rq = l >> 4, cl = l & 15;
#pragma unroll
    for (int q = 0; q < 4; ++q) {
        int rr = r0 + rq * 4 + q;
        float d = dinv[rr];
        uint4 w;
        w.x = (unsigned)f2bf(acc[0][q] * d) | ((unsigned)f2bf(acc[1][q] * d) << 16);
        w.y = (unsigned)f2bf(acc[2][q] * d) | ((unsigned)f2bf(acc[3][q] * d) << 16);
        w.z = (unsigned)f2bf(acc[4][q] * d) | ((unsigned)f2bf(acc[5][q] * d) << 16);
        w.w = (unsigned)f2bf(acc[6][q] * d) | ((unsigned)f2bf(acc[7][q] * d) << 16);
        *(uint4*)(outb + (size_t)rr * 64 + cl * 4) = w;
    }
}

// ---------------------------------------------------------------- agg conv0: gather-sum bf16 rows, relu, write bf16 P1
__global__ __launch_bounds__(256) void k_agg0(const unsigned* __restrict__ hp, const int* __restrict__ offs,
                                              const int* __restrict__ src, const float* __restrict__ dinv,
                                              const float* __restrict__ bp, unsigned* __restrict__ outb, int n) {
    int wid = (blockIdx.x * 256 + threadIdx.x) >> 6;
    int l = threadIdx.x & 63;
    if (wid >= n) return;
    unsigned u = hp[(size_t)wid * 64 + l];
    float ax = bflo(u), ay = bfhi(u);
    int beg = offs[wid], end = offs[wid + 1];
    int e = beg;
    for (; e + 4 <= end; e += 4) {
        int s0 = src[e], s1 = src[e + 1], s2 = src[e + 2], s3 = src[e + 3];
        unsigned v0 = hp[(size_t)s0 * 64 + l];
        unsigned v1 = hp[(size_t)s1 * 64 + l];
        unsigned v2 = hp[(size_t)s2 * 64 + l];
        unsigned v3 = hp[(size_t)s3 * 64 + l];
        ax += bflo(v0) + bflo(v1) + bflo(v2) + bflo(v3);
        ay += bfhi(v0) + bfhi(v1) + bfhi(v2) + bfhi(v3);
    }
    for (; e < end; ++e) {
        unsigned v = hp[(size_t)src[e] * 64 + l];
        ax += bflo(v); ay += bfhi(v);
    }
    float d = dinv[wid];
    float2 b = ((const float2*)bp)[l];
    float ox = fmaxf(fmaf(d, ax, b.x), 0.f);
    float oy = fmaxf(fmaf(d, ay, b.y), 0.f);
    outb[(size_t)wid * 64 + l] = (unsigned)f2bf(ox) | ((unsigned)f2bf(oy) << 16);
}

// ---------------------------------------------------------------- agg conv1 + fused segment-max pool
__global__ __launch_bounds__(256) void k_agg1(const unsigned* __restrict__ hp, const int* __restrict__ offs,
                                              const int* __restrict__ src, const float* __restrict__ dinv,
                                              const float* __restrict__ bp, const int* __restrict__ batch,
                                              int* __restrict__ pool, int n) {
    __shared__ float2 sv[4][64];
    __shared__ int sg[4];
    int w = threadIdx.x >> 6, l = threadIdx.x & 63;
    int wid = blockIdx.x * 4 + w;
    float ox = 0.f, oy = 0.f;
    if (wid < n) {
        unsigned u = hp[(size_t)wid * 64 + l];
        float ax = bflo(u), ay = bfhi(u);
        int beg = offs[wid], end = offs[wid + 1];
        int e = beg;
        for (; e + 4 <= end; e += 4) {
            int s0 = src[e], s1 = src[e + 1], s2 = src[e + 2], s3 = src[e + 3];
            unsigned v0 = hp[(size_t)s0 * 64 + l];
            unsigned v1 = hp[(size_t)s1 * 64 + l];
            unsigned v2 = hp[(size_t)s2 * 64 + l];
            unsigned v3 = hp[(size_t)s3 * 64 + l];
            ax += bflo(v0) + bflo(v1) + bflo(v2) + bflo(v3);
            ay += bfhi(v0) + bfhi(v1) + bfhi(v2) + bfhi(v3);
        }
        for (; e < end; ++e) {
            unsigned v = hp[(size_t)src[e] * 64 + l];
            ax += bflo(v); ay += bfhi(v);
        }
        float d = dinv[wid];
        float2 b = ((const float2*)bp)[l];
        ox = fmaxf(fmaf(d, ax, b.x), 0.f);
        oy = fmaxf(fmaf(d, ay, b.y), 0.f);
        if (l == 0) sg[w] = batch[wid];
    } else if (l == 0) {
        sg[w] = -1;
    }
    sv[w][l] = make_float2(ox, oy);
    __syncthreads();
    if (threadIdx.x < 64) {
        int t = threadIdx.x;
        int c0 = 32 * (t & 3) + (t >> 2);           // true col of position 2t; pair col = c0+16
        int cur = sg[0];
        float2 m = sv[0][t];
        for (int ww = 1; ww < 4; ++ww) {
            int g = sg[ww];
            if (g < 0) break;                        // batch sorted; invalid only at tail
            float2 v = sv[ww][t];
            if (g == cur) { m.x = fmaxf(m.x, v.x); m.y = fmaxf(m.y, v.y); }
            else {
                atomicMax(&pool[cur * 128 + c0], __float_as_int(m.x));
                atomicMax(&pool[cur * 128 + c0 + 16], __float_as_int(m.y));
                cur = g; m = v;
            }
        }
        atomicMax(&pool[cur * 128 + c0], __float_as_int(m.x));
        atomicMax(&pool[cur * 128 + c0 + 16], __float_as_int(m.y));
    }
}

// ---------------------------------------------------------------- pool init
__global__ __launch_bounds__(128) void k_pool_init(int* __restrict__ pool) {
    pool[blockIdx.x * 128 + threadIdx.x] = 0;
}

// ---------------------------------------------------------------- final MLP + log_softmax, 1 block/graph
__global__ __launch_bounds__(128) void k_mlp(const float* __restrict__ pool, const float* __restrict__ W0,
                                             const float* __restrict__ b0, const float* __restrict__ W1,
                                             const float* __restrict__ b1, float* __restrict__ out) {
    __shared__ float rowv[128];
    __shared__ float h2[128];
    __shared__ float h3[10];
    int g = blockIdx.x, t = threadIdx.x;
    rowv[t] = pool[g * 128 + t];
    __syncthreads();
    float acc = b0[t];
    for (int k = 0; k < 128; ++k) acc = fmaf(rowv[k], W0[k * 128 + t], acc);
    h2[t] = fmaxf(acc, 0.f);
    __syncthreads();
    if (t < 10) {
        float a = b1[t];
        for (int k = 0; k < 128; ++k) a = fmaf(h2[k], W1[k * 10 + t], a);
        h3[t] = fmaxf(a, 0.f);
    }
    __syncthreads();
    if (t == 0) {
        float mx = h3[0];
        for (int j = 1; j < 10; ++j) mx = fmaxf(mx, h3[j]);
        float s = 0.f;
        for (int j = 0; j < 10; ++j) s += expf(h3[j] - mx);
        float lse = logf(s) + mx;
        for (int j = 0; j < 10; ++j) out[g * 10 + j] = h3[j] - lse;
    }
}

// ----------------------------------------------------------------
extern "C" void kernel_launch(void* const* d_in, const int* in_sizes, int n_in,
                              void* d_out, int out_size, void* d_ws, size_t ws_size,
                              hipStream_t stream) {
    const float* x   = (const float*)d_in[0];
    const int* eidx  = (const int*)d_in[1];
    const int* batch = (const int*)d_in[2];
    const float* w0  = (const float*)d_in[3];
    const float* b0  = (const float*)d_in[4];
    const float* w1  = (const float*)d_in[5];
    const float* b1  = (const float*)d_in[6];
    const float* lw0 = (const float*)d_in[7];
    const float* lb0 = (const float*)d_in[8];
    const float* lw1 = (const float*)d_in[9];
    const float* lb1 = (const float*)d_in[10];
    float* out = (float*)d_out;

    int n = in_sizes[2];
    int E = in_sizes[1] / 2;
    const int* row = eidx;        // sources
    const int* col = eidx + E;    // destinations
    int nTiles = (n + TILE - 1) / TILE;

    char* ws = (char*)d_ws;
    size_t o = 0;
    auto take = [&](size_t bytes) { void* p = ws + o; o += (bytes + 255) & ~(size_t)255; return p; };
    int*      deg      = (int*)     take((size_t)n * 4);
    int*      offsets  = (int*)     take((size_t)(n + 1) * 4);
    int*      cursor   = (int*)     take((size_t)n * 4);
    int*      csr      = (int*)     take((size_t)E * 4);
    float*    dinv     = (float*)   take((size_t)n * 4);
    int*      tileSum  = (int*)     take((size_t)nTiles * 4);
    int*      tileBase = (int*)     take((size_t)nTiles * 4);
    uint4*    Wp0      = (uint4*)   take(2048 * 16);
    uint4*    Wp1      = (uint4*)   take(2048 * 16);
    float*    b0p      = (float*)   take(128 * 4);
    float*    b1p      = (float*)   take(128 * 4);
    unsigned* h0b      = (unsigned*)take((size_t)n * 64 * 4);   // bf16 P1 rows
    unsigned* h1i      = (unsigned*)take((size_t)n * 64 * 4);
    unsigned* h1b      = (unsigned*)take((size_t)n * 64 * 4);
    int*      pool     = (int*)     take(64 * 128 * 4);

    k_deg_init<<<(n + 255) / 256, 256, 0, stream>>>(deg, n);
    k_count<<<(E + 255) / 256, 256, 0, stream>>>(col, deg, E);
    k_tilesum<<<nTiles, TILE, 0, stream>>>(deg, tileSum, n);
    k_tilescan<<<1, TILE, 0, stream>>>(tileSum, tileBase, &offsets[n], nTiles);
    k_offsets<<<nTiles, TILE, 0, stream>>>(deg, tileBase, offsets, cursor, dinv, n);
    k_fill<<<(E + 255) / 256, 256, 0, stream>>>(row, col, cursor, csr, E);
    k_packW<<<1, 256, 0, stream>>>(w0, w1, b0, b1, Wp0, Wp1, b0p, b1p);
    k_pool_init<<<64, 128, 0, stream>>>(pool);

    int mtBlocks = ((n + 15) / 16 + 3) / 4;     // 4 waves/block, 1 mtile/wave

    // conv0
    k_gemm0<<<mtBlocks, 256, 0, stream>>>(x, Wp0, dinv, h0b, n);
    k_agg0<<<(n + 3) / 4, 256, 0, stream>>>(h0b, offsets, csr, dinv, b0p, h1i, n);
    // conv1 (+ fused pool)
    k_gemm1<<<mtBlocks, 256, 0, stream>>>(h1i, Wp1, dinv, h1b, n);
    k_agg1<<<(n + 3) / 4, 256, 0, stream>>>(h1b, offsets, csr, dinv, b1p, batch, pool, n);

    k_mlp<<<64, 128, 0, stream>>>((const float*)pool, lw0, lb0, lw1, lb1, out);
}

// Round 6
// 300.600 us; speedup vs baseline: 1.5101x; 1.0264x over previous
//
#include <hip/hip_runtime.h>

#define D 128
#define TILE 256

typedef __attribute__((ext_vector_type(8))) short short8;
typedef __attribute__((ext_vector_type(4))) float f32x4;

__device__ inline unsigned short f2bf(float f) {
    unsigned u = __float_as_uint(f);
    return (unsigned short)((u + 0x7FFFu + ((u >> 16) & 1u)) >> 16);
}
__device__ inline float bflo(unsigned u) { return __uint_as_float(u << 16); }
__device__ inline float bfhi(unsigned u) { return __uint_as_float(u & 0xFFFF0000u); }

// ---------------------------------------------------------------- degree init
__global__ __launch_bounds__(256) void k_deg_init(int* __restrict__ deg, int n) {
    int i = blockIdx.x * 256 + threadIdx.x;
    if (i < n) deg[i] = 1;  // self-loop
}

// ---------------------------------------------------------------- degree count
__global__ __launch_bounds__(256) void k_count(const int* __restrict__ col, int* __restrict__ deg, int E) {
    int e = blockIdx.x * 256 + threadIdx.x;
    if (e < E) atomicAdd(&deg[col[e]], 1);
}

// ---------------------------------------------------------------- scan phase 1
__global__ __launch_bounds__(TILE) void k_tilesum(const int* __restrict__ deg, int* __restrict__ tileSum, int n) {
    __shared__ int s[TILE];
    int t = threadIdx.x;
    int i = blockIdx.x * TILE + t;
    s[t] = (i < n) ? deg[i] - 1 : 0;
    __syncthreads();
    for (int off = TILE / 2; off > 0; off >>= 1) {
        if (t < off) s[t] += s[t + off];
        __syncthreads();
    }
    if (t == 0) tileSum[blockIdx.x] = s[0];
}

// ---------------------------------------------------------------- scan phase 2 (1 block)
__global__ __launch_bounds__(TILE) void k_tilescan(const int* __restrict__ tileSum, int* __restrict__ tileBase,
                                                   int* __restrict__ total_out, int nTiles) {
    __shared__ int s[TILE];
    int t = threadIdx.x;
    int v = (t < nTiles) ? tileSum[t] : 0;
    s[t] = v;
    __syncthreads();
    for (int off = 1; off < TILE; off <<= 1) {
        int tmp = (t >= off) ? s[t - off] : 0;
        __syncthreads();
        s[t] += tmp;
        __syncthreads();
    }
    if (t < nTiles) tileBase[t] = s[t] - v;
    if (t == TILE - 1) total_out[0] = s[TILE - 1];
}

// ---------------------------------------------------------------- scan phase 3
__global__ __launch_bounds__(TILE) void k_offsets(const int* __restrict__ deg, const int* __restrict__ tileBase,
                                                  int* __restrict__ offsets, int* __restrict__ cursor,
                                                  float* __restrict__ dinv, int n) {
    __shared__ int s[TILE];
    int t = threadIdx.x;
    int i = blockIdx.x * TILE + t;
    int dg = (i < n) ? deg[i] : 1;
    int v = dg - 1;
    s[t] = v;
    __syncthreads();
    for (int off = 1; off < TILE; off <<= 1) {
        int tmp = (t >= off) ? s[t - off] : 0;
        __syncthreads();
        s[t] += tmp;
        __syncthreads();
    }
    if (i < n) {
        int excl = s[t] - v + tileBase[blockIdx.x];
        offsets[i] = excl;
        cursor[i] = excl;
        dinv[i] = rsqrtf((float)dg);
    }
}

// ---------------------------------------------------------------- CSR fill
__global__ __launch_bounds__(256) void k_fill(const int* __restrict__ row, const int* __restrict__ col,
                                              int* __restrict__ cursor, int* __restrict__ csr, int E) {
    int e = blockIdx.x * 256 + threadIdx.x;
    if (e < E) {
        int d = col[e];
        int p = atomicAdd(&cursor[d], 1);
        csr[p] = row[e];
    }
}

// ---------------------------------------------------------------- pack W0 (natural k), W1 (P1-permuted k), biases (P1 positions)
__global__ __launch_bounds__(256) void k_packW(const float* __restrict__ w0, const float* __restrict__ w1,
                                               const float* __restrict__ b0, const float* __restrict__ b1,
                                               uint4* __restrict__ Wp0, uint4* __restrict__ Wp1,
                                               float* __restrict__ b0p, float* __restrict__ b1p) {
    int t = threadIdx.x;
    for (int e = t; e < 2048; e += 256) {
        int l = e & 63, U = (e >> 6) & 7, T = e >> 9;
        int nn = U * 16 + (l & 15);
        int kq = T * 32 + ((l >> 4) << 3);
        unsigned r[4], s[4];
#pragma unroll
        for (int jj = 0; jj < 4; ++jj) {
            int k0 = kq + 2 * jj, k1 = k0 + 1;
            unsigned a0 = f2bf(w0[k0 * 128 + nn]), a1 = f2bf(w0[k1 * 128 + nn]);
            r[jj] = a0 | (a1 << 16);
            int c0 = ((k0 & 7) << 4) | (k0 >> 3), c1 = ((k1 & 7) << 4) | (k1 >> 3);
            unsigned q0 = f2bf(w1[c0 * 128 + nn]), q1 = f2bf(w1[c1 * 128 + nn]);
            s[jj] = q0 | (q1 << 16);
        }
        Wp0[e] = make_uint4(r[0], r[1], r[2], r[3]);
        Wp1[e] = make_uint4(s[0], s[1], s[2], s[3]);
    }
    if (t < 128) {
        int c = ((t & 7) << 4) | (t >> 3);
        b0p[t] = b0[c];
        b1p[t] = b1[c];
    }
}

// ---------------------------------------------------------------- MFMA GEMM, fp32 row-major input (conv0)
__global__ __launch_bounds__(256) void k_gemm0(const float* __restrict__ x, const uint4* __restrict__ Wp,
                                               const float* __restrict__ dinv, unsigned* __restrict__ outb, int n) {
    int wave = threadIdx.x >> 6, l = threadIdx.x & 63;
    int mt = blockIdx.x * 4 + wave;
    int r0 = mt * 16;
    if (r0 >= n) return;                    // n % 16 == 0
    int rowA = r0 + (l & 15);
    int kq = (l >> 4) * 8;
    f32x4 acc[8];
#pragma unroll
    for (int U = 0; U < 8; ++U) acc[U] = (f32x4){0.f, 0.f, 0.f, 0.f};
    const float* xr = x + (size_t)rowA * 128 + kq;
#pragma unroll
    for (int T = 0; T < 4; ++T) {
        float4 a0 = *(const float4*)(xr + T * 32);
        float4 a1 = *(const float4*)(xr + T * 32 + 4);
        short8 af;
        af[0] = (short)f2bf(a0.x); af[1] = (short)f2bf(a0.y);
        af[2] = (short)f2bf(a0.z); af[3] = (short)f2bf(a0.w);
        af[4] = (short)f2bf(a1.x); af[5] = (short)f2bf(a1.y);
        af[6] = (short)f2bf(a1.z); af[7] = (short)f2bf(a1.w);
#pragma unroll
        for (int U = 0; U < 8; ++U) {
            short8 bf = *(const short8*)&Wp[(T * 8 + U) * 64 + l];
            acc[U] = __builtin_amdgcn_mfma_f32_16x16x32_bf16(af, bf, acc[U], 0, 0, 0);
        }
    }
    int rq = l >> 4, cl = l & 15;
#pragma unroll
    for (int q = 0; q < 4; ++q) {
        int rr = r0 + rq * 4 + q;
        float d = dinv[rr];
        uint4 w;
        w.x = (unsigned)f2bf(acc[0][q] * d) | ((unsigned)f2bf(acc[1][q] * d) << 16);
        w.y = (unsigned)f2bf(acc[2][q] * d) | ((unsigned)f2bf(acc[3][q] * d) << 16);
        w.z = (unsigned)f2bf(acc[4][q] * d) | ((unsigned)f2bf(acc[5][q] * d) << 16);
        w.w = (unsigned)f2bf(acc[6][q] * d) | ((unsigned)f2bf(acc[7][q] * d) << 16);
        *(uint4*)(outb + (size_t)rr * 64 + cl * 4) = w;
    }
}

// ---------------------------------------------------------------- MFMA GEMM, bf16 P1-ordered input (conv1)
__global__ __launch_bounds__(256) void k_gemm1(const unsigned* __restrict__ inb, const uint4* __restrict__ Wp,
                                               const float* __restrict__ dinv, unsigned* __restrict__ outb, int n) {
    int wave = threadIdx.x >> 6, l = threadIdx.x & 63;
    int mt = blockIdx.x * 4 + wave;
    int r0 = mt * 16;
    if (r0 >= n) return;
    int rowA = r0 + (l & 15);
    int kq4 = (l >> 4) * 4;                 // dword offset of 8-bf16 group
    f32x4 acc[8];
#pragma unroll
    for (int U = 0; U < 8; ++U) acc[U] = (f32x4){0.f, 0.f, 0.f, 0.f};
    const unsigned* ir = inb + (size_t)rowA * 64 + kq4;
#pragma unroll
    for (int T = 0; T < 4; ++T) {
        short8 af = *(const short8*)(ir + T * 16);
#pragma unroll
        for (int U = 0; U < 8; ++U) {
            short8 bf = *(const short8*)&Wp[(T * 8 + U) * 64 + l];
            acc[U] = __builtin_amdgcn_mfma_f32_16x16x32_bf16(af, bf, acc[U], 0, 0, 0);
        }
    }
    int rq = l >> 4, cl = l & 15;
#pragma unroll
    for (int q = 0; q < 4; ++q) {
        int rr = r0 + rq * 4 + q;
        float d = dinv[rr];
        uint4 w;
        w.x = (unsigned)f2bf(acc[0][q] * d) | ((unsigned)f2bf(acc[1][q] * d) << 16);
        w.y = (unsigned)f2bf(acc[2][q] * d) | ((unsigned)f2bf(acc[3][q] * d) << 16);
        w.z = (unsigned)f2bf(acc[4][q] * d) | ((unsigned)f2bf(acc[5][q] * d) << 16);
        w.w = (unsigned)f2bf(acc[6][q] * d) | ((unsigned)f2bf(acc[7][q] * d) << 16);
        *(uint4*)(outb + (size_t)rr * 64 + cl * 4) = w;
    }
}

// ---------------------------------------------------------------- dual-stream gather-sum core
// Splits [beg,end) into two halves; 4-deep unroll per stream -> 8 outstanding row loads.
__device__ inline void gather2(const unsigned* __restrict__ hp, const int* __restrict__ src,
                               int l, int beg, int end, float& AX, float& AY) {
    int len = end - beg;
    int h = len >> 1;
    int e0 = beg, end0 = beg + h;
    int e1 = end0, end1 = end;
    float ax0 = 0.f, ay0 = 0.f, ax1 = 0.f, ay1 = 0.f;
    while (e0 + 4 <= end0 && e1 + 4 <= end1) {
        int a0 = src[e0], a1 = src[e0 + 1], a2 = src[e0 + 2], a3 = src[e0 + 3];
        int b0 = src[e1], b1 = src[e1 + 1], b2 = src[e1 + 2], b3 = src[e1 + 3];
        unsigned u0 = hp[(size_t)a0 * 64 + l];
        unsigned u1 = hp[(size_t)a1 * 64 + l];
        unsigned u2 = hp[(size_t)a2 * 64 + l];
        unsigned u3 = hp[(size_t)a3 * 64 + l];
        unsigned u4 = hp[(size_t)b0 * 64 + l];
        unsigned u5 = hp[(size_t)b1 * 64 + l];
        unsigned u6 = hp[(size_t)b2 * 64 + l];
        unsigned u7 = hp[(size_t)b3 * 64 + l];
        ax0 += bflo(u0) + bflo(u1) + bflo(u2) + bflo(u3);
        ay0 += bfhi(u0) + bfhi(u1) + bfhi(u2) + bfhi(u3);
        ax1 += bflo(u4) + bflo(u5) + bflo(u6) + bflo(u7);
        ay1 += bfhi(u4) + bfhi(u5) + bfhi(u6) + bfhi(u7);
        e0 += 4; e1 += 4;
    }
    for (; e0 < end0; ++e0) {
        unsigned v = hp[(size_t)src[e0] * 64 + l];
        ax0 += bflo(v); ay0 += bfhi(v);
    }
    for (; e1 < end1; ++e1) {
        unsigned v = hp[(size_t)src[e1] * 64 + l];
        ax1 += bflo(v); ay1 += bfhi(v);
    }
    AX += ax0 + ax1;
    AY += ay0 + ay1;
}

// ---------------------------------------------------------------- agg conv0: gather-sum bf16 rows, relu, write bf16 P1
__global__ __launch_bounds__(256) void k_agg0(const unsigned* __restrict__ hp, const int* __restrict__ offs,
                                              const int* __restrict__ src, const float* __restrict__ dinv,
                                              const float* __restrict__ bp, unsigned* __restrict__ outb, int n) {
    int wid = (blockIdx.x * 256 + threadIdx.x) >> 6;
    int l = threadIdx.x & 63;
    if (wid >= n) return;
    unsigned u = hp[(size_t)wid * 64 + l];
    float ax = bflo(u), ay = bfhi(u);
    gather2(hp, src, l, offs[wid], offs[wid + 1], ax, ay);
    float d = dinv[wid];
    float2 b = ((const float2*)bp)[l];
    float ox = fmaxf(fmaf(d, ax, b.x), 0.f);
    float oy = fmaxf(fmaf(d, ay, b.y), 0.f);
    outb[(size_t)wid * 64 + l] = (unsigned)f2bf(ox) | ((unsigned)f2bf(oy) << 16);
}

// ---------------------------------------------------------------- agg conv1 + fused segment-max pool
__global__ __launch_bounds__(256) void k_agg1(const unsigned* __restrict__ hp, const int* __restrict__ offs,
                                              const int* __restrict__ src, const float* __restrict__ dinv,
                                              const float* __restrict__ bp, const int* __restrict__ batch,
                                              int* __restrict__ pool, int n) {
    __shared__ float2 sv[4][64];
    __shared__ int sg[4];
    int w = threadIdx.x >> 6, l = threadIdx.x & 63;
    int wid = blockIdx.x * 4 + w;
    float ox = 0.f, oy = 0.f;
    if (wid < n) {
        unsigned u = hp[(size_t)wid * 64 + l];
        float ax = bflo(u), ay = bfhi(u);
        gather2(hp, src, l, offs[wid], offs[wid + 1], ax, ay);
        float d = dinv[wid];
        float2 b = ((const float2*)bp)[l];
        ox = fmaxf(fmaf(d, ax, b.x), 0.f);
        oy = fmaxf(fmaf(d, ay, b.y), 0.f);
        if (l == 0) sg[w] = batch[wid];
    } else if (l == 0) {
        sg[w] = -1;
    }
    sv[w][l] = make_float2(ox, oy);
    __syncthreads();
    if (threadIdx.x < 64) {
        int t = threadIdx.x;
        int c0 = 32 * (t & 3) + (t >> 2);           // true col of position 2t; pair col = c0+16
        int cur = sg[0];
        float2 m = sv[0][t];
        for (int ww = 1; ww < 4; ++ww) {
            int g = sg[ww];
            if (g < 0) break;                        // batch sorted; invalid only at tail
            float2 v = sv[ww][t];
            if (g == cur) { m.x = fmaxf(m.x, v.x); m.y = fmaxf(m.y, v.y); }
            else {
                atomicMax(&pool[cur * 128 + c0], __float_as_int(m.x));
                atomicMax(&pool[cur * 128 + c0 + 16], __float_as_int(m.y));
                cur = g; m = v;
            }
        }
        atomicMax(&pool[cur * 128 + c0], __float_as_int(m.x));
        atomicMax(&pool[cur * 128 + c0 + 16], __float_as_int(m.y));
    }
}

// ---------------------------------------------------------------- pool init
__global__ __launch_bounds__(128) void k_pool_init(int* __restrict__ pool) {
    pool[blockIdx.x * 128 + threadIdx.x] = 0;
}

// ---------------------------------------------------------------- final MLP + log_softmax, 1 block/graph
__global__ __launch_bounds__(128) void k_mlp(const float* __restrict__ pool, const float* __restrict__ W0,
                                             const float* __restrict__ b0, const float* __restrict__ W1,
                                             const float* __restrict__ b1, float* __restrict__ out) {
    __shared__ float rowv[128];
    __shared__ float h2[128];
    __shared__ float h3[10];
    int g = blockIdx.x, t = threadIdx.x;
    rowv[t] = pool[g * 128 + t];
    __syncthreads();
    float acc = b0[t];
    for (int k = 0; k < 128; ++k) acc = fmaf(rowv[k], W0[k * 128 + t], acc);
    h2[t] = fmaxf(acc, 0.f);
    __syncthreads();
    if (t < 10) {
        float a = b1[t];
        for (int k = 0; k < 128; ++k) a = fmaf(h2[k], W1[k * 10 + t], a);
        h3[t] = fmaxf(a, 0.f);
    }
    __syncthreads();
    if (t == 0) {
        float mx = h3[0];
        for (int j = 1; j < 10; ++j) mx = fmaxf(mx, h3[j]);
        float s = 0.f;
        for (int j = 0; j < 10; ++j) s += expf(h3[j] - mx);
        float lse = logf(s) + mx;
        for (int j = 0; j < 10; ++j) out[g * 10 + j] = h3[j] - lse;
    }
}

// ----------------------------------------------------------------
extern "C" void kernel_launch(void* const* d_in, const int* in_sizes, int n_in,
                              void* d_out, int out_size, void* d_ws, size_t ws_size,
                              hipStream_t stream) {
    const float* x   = (const float*)d_in[0];
    const int* eidx  = (const int*)d_in[1];
    const int* batch = (const int*)d_in[2];
    const float* w0  = (const float*)d_in[3];
    const float* b0  = (const float*)d_in[4];
    const float* w1  = (const float*)d_in[5];
    const float* b1  = (const float*)d_in[6];
    const float* lw0 = (const float*)d_in[7];
    const float* lb0 = (const float*)d_in[8];
    const float* lw1 = (const float*)d_in[9];
    const float* lb1 = (const float*)d_in[10];
    float* out = (float*)d_out;

    int n = in_sizes[2];
    int E = in_sizes[1] / 2;
    const int* row = eidx;        // sources
    const int* col = eidx + E;    // destinations
    int nTiles = (n + TILE - 1) / TILE;

    char* ws = (char*)d_ws;
    size_t o = 0;
    auto take = [&](size_t bytes) { void* p = ws + o; o += (bytes + 255) & ~(size_t)255; return p; };
    int*      deg      = (int*)     take((size_t)n * 4);
    int*      offsets  = (int*)     take((size_t)(n + 1) * 4);
    int*      cursor   = (int*)     take((size_t)n * 4);
    int*      csr      = (int*)     take((size_t)E * 4);
    float*    dinv     = (float*)   take((size_t)n * 4);
    int*      tileSum  = (int*)     take((size_t)nTiles * 4);
    int*      tileBase = (int*)     take((size_t)nTiles * 4);
    uint4*    Wp0      = (uint4*)   take(2048 * 16);
    uint4*    Wp1      = (uint4*)   take(2048 * 16);
    float*    b0p      = (float*)   take(128 * 4);
    float*    b1p      = (float*)   take(128 * 4);
    unsigned* h0b      = (unsigned*)take((size_t)n * 64 * 4);   // bf16 P1 rows
    unsigned* h1i      = (unsigned*)take((size_t)n * 64 * 4);
    unsigned* h1b      = (unsigned*)take((size_t)n * 64 * 4);
    int*      pool     = (int*)     take(64 * 128 * 4);

    k_deg_init<<<(n + 255) / 256, 256, 0, stream>>>(deg, n);
    k_count<<<(E + 255) / 256, 256, 0, stream>>>(col, deg, E);
    k_tilesum<<<nTiles, TILE, 0, stream>>>(deg, tileSum, n);
    k_tilescan<<<1, TILE, 0, stream>>>(tileSum, tileBase, &offsets[n], nTiles);
    k_offsets<<<nTiles, TILE, 0, stream>>>(deg, tileBase, offsets, cursor, dinv, n);
    k_fill<<<(E + 255) / 256, 256, 0, stream>>>(row, col, cursor, csr, E);
    k_packW<<<1, 256, 0, stream>>>(w0, w1, b0, b1, Wp0, Wp1, b0p, b1p);
    k_pool_init<<<64, 128, 0, stream>>>(pool);

    int mtBlocks = ((n + 15) / 16 + 3) / 4;     // 4 waves/block, 1 mtile/wave

    // conv0
    k_gemm0<<<mtBlocks, 256, 0, stream>>>(x, Wp0, dinv, h0b, n);
    k_agg0<<<(n + 3) / 4, 256, 0, stream>>>(h0b, offsets, csr, dinv, b0p, h1i, n);
    // conv1 (+ fused pool)
    k_gemm1<<<mtBlocks, 256, 0, stream>>>(h1i, Wp1, dinv, h1b, n);
    k_agg1<<<(n + 3) / 4, 256, 0, stream>>>(h1b, offsets, csr, dinv, b1p, batch, pool, n);

    k_mlp<<<64, 128, 0, stream>>>((const float*)pool, lw0, lb0, lw1, lb1, out);
}